// Round 1
// baseline (416.620 us; speedup 1.0000x reference)
//
#include <hip/hip_runtime.h>
#include <math.h>

// Problem constants (from reference setup_inputs)
#define BB 4
#define NN 100
#define MM 20
#define HWPIX 65536

constexpr float ALPHA_C = 0.25f;

// ---------------------------------------------------------------------------
// Kernel A: pack the M binary target masks into a per-pixel 20-bit bitfield,
// and accumulate per-(b,m) target sums (tsum) via wave-reduce + atomicAdd.
// Grid: BB*64 blocks, 256 threads; each block handles 1024 pixels of one b.
// ---------------------------------------------------------------------------
__global__ __launch_bounds__(256) void pack_targets_kernel(
    const float* __restrict__ tgt,       // [B][M][HW]
    unsigned int* __restrict__ masks,    // [B][HW]
    float* __restrict__ tsum)            // [B][M] (pre-zeroed)
{
    const int b    = blockIdx.x >> 6;        // 64 blocks per batch
    const int blk  = blockIdx.x & 63;
    const int base = blk * 1024;
    const int tid  = threadIdx.x;

    float sums[MM];
#pragma unroll
    for (int m = 0; m < MM; ++m) sums[m] = 0.f;

    const float* tb = tgt + (size_t)b * MM * HWPIX;

    for (int i = 0; i < 4; ++i) {
        const int c = base + i * 256 + tid;
        unsigned int mask = 0;
#pragma unroll
        for (int m = 0; m < MM; ++m) {
            float t = tb[(size_t)m * HWPIX + c];   // coalesced across tid
            sums[m] += t;                          // t is exactly 0.0 or 1.0
            mask |= (t > 0.5f) ? (1u << m) : 0u;
        }
        masks[(size_t)b * HWPIX + c] = mask;
    }

    // wave-level reduce each per-m sum, lane 0 of each wave atomics it in
    const int lane = tid & 63;
#pragma unroll
    for (int m = 0; m < MM; ++m) {
        float v = sums[m];
        for (int off = 32; off > 0; off >>= 1) v += __shfl_down(v, off, 64);
        if (lane == 0) atomicAdd(&tsum[b * MM + m], v);
    }
}

// ---------------------------------------------------------------------------
// Kernel B: per (b,n) block, stream over HW pixels computing per-pixel
// focal/sigmoid terms and accumulating:
//   d1[m] = sum_c t[m,c] * (focal_pos - focal_neg)
//   d2[m] = sum_c t[m,c] * prob
//   sum_fn = sum_c focal_neg ;  sum_p = sum_c prob
// then: cost_mask = (sum_fn + d1[m]) / HW
//       dice      = 1 - (2*d2[m] + 1) / (sum_p + tsum[b,m] + 1)
// ---------------------------------------------------------------------------
__global__ __launch_bounds__(256) void cost_kernel(
    const float* __restrict__ out,             // [B][N][HW]
    const unsigned int* __restrict__ masks,    // [B][HW]
    const float* __restrict__ tsum,            // [B][M]
    float* __restrict__ C)                     // [B][N][M]
{
    const int bn  = blockIdx.x;                // b*N + n
    const int b   = bn / NN;
    const int tid = threadIdx.x;

    const float* xp        = out + (size_t)bn * HWPIX;
    const unsigned int* mp = masks + (size_t)b * HWPIX;

    float d1[MM], d2[MM];
#pragma unroll
    for (int m = 0; m < MM; ++m) { d1[m] = 0.f; d2[m] = 0.f; }
    float sum_fn = 0.f, sum_p = 0.f;

    for (int it = 0; it < HWPIX / 256; ++it) {
        const int c = it * 256 + tid;          // coalesced
        const float x = xp[c];
        const unsigned int mk = mp[c];

        // Stable focal terms:
        //   e  = exp(-|x|);  L = log(1+e)
        //   softplus(x)  = relu(x) + L       (= bce_neg)
        //   softplus(-x) = relu(x) - x + L   (= bce_pos)
        //   p = (x>=0 ? 1 : e) / (1+e)
        const float ax  = fabsf(x);
        const float e   = __expf(-ax);
        const float L   = __logf(1.f + e);
        const float rlx = fmaxf(x, 0.f);
        const float bce_neg = rlx + L;
        const float bce_pos = rlx - x + L;
        const float inv = __builtin_amdgcn_rcpf(1.f + e);
        const float p   = (x >= 0.f ? 1.f : e) * inv;
        const float omp = 1.f - p;
        const float fpv = ALPHA_C * omp * omp * bce_pos;
        const float fnv = (1.f - ALPHA_C) * p * p * bce_neg;
        const float diff = fpv - fnv;

        sum_fn += fnv;
        sum_p  += p;

#pragma unroll
        for (int m = 0; m < MM; ++m) {
            const float tm = (float)((mk >> m) & 1u);   // bfe + cvt
            d1[m] = fmaf(tm, diff, d1[m]);
            d2[m] = fmaf(tm, p,    d2[m]);
        }
    }

    // ---- block reduction: 42 values per thread ----
    __shared__ float red[4][42];
    const int wave = tid >> 6;
    const int lane = tid & 63;

#pragma unroll
    for (int m = 0; m < MM; ++m) {
        for (int off = 32; off > 0; off >>= 1) {
            d1[m] += __shfl_down(d1[m], off, 64);
            d2[m] += __shfl_down(d2[m], off, 64);
        }
    }
    for (int off = 32; off > 0; off >>= 1) {
        sum_fn += __shfl_down(sum_fn, off, 64);
        sum_p  += __shfl_down(sum_p,  off, 64);
    }
    if (lane == 0) {
#pragma unroll
        for (int m = 0; m < MM; ++m) {
            red[wave][m]      = d1[m];
            red[wave][MM + m] = d2[m];
        }
        red[wave][40] = sum_fn;
        red[wave][41] = sum_p;
    }
    __syncthreads();

    if (tid < MM) {
        float D1 = 0.f, D2 = 0.f, SFN = 0.f, SP = 0.f;
#pragma unroll
        for (int w = 0; w < 4; ++w) {
            D1  += red[w][tid];
            D2  += red[w][MM + tid];
            SFN += red[w][40];
            SP  += red[w][41];
        }
        const float cost_mask = (SFN + D1) * (1.f / (float)HWPIX);
        const float den  = SP + tsum[b * MM + tid];
        const float num  = 2.f * D2;
        const float dice = 1.f - (num + 1.f) / (den + 1.f);
        C[(size_t)bn * MM + tid] = cost_mask + dice;
    }
}

extern "C" void kernel_launch(void* const* d_in, const int* in_sizes, int n_in,
                              void* d_out, int out_size, void* d_ws, size_t ws_size,
                              hipStream_t stream)
{
    const float* outp = (const float*)d_in[0];   // [B][N][H][W]
    const float* tgtp = (const float*)d_in[1];   // [B][M][H][W]
    float* C = (float*)d_out;                    // [B][N][M]

    unsigned int* masks = (unsigned int*)d_ws;                       // B*HW uints = 1 MB
    float* tsum = (float*)((char*)d_ws + (size_t)BB * HWPIX * sizeof(unsigned int)); // B*M floats

    hipMemsetAsync(tsum, 0, (size_t)BB * MM * sizeof(float), stream);

    pack_targets_kernel<<<BB * 64, 256, 0, stream>>>(tgtp, masks, tsum);
    cost_kernel<<<BB * NN, 256, 0, stream>>>(outp, masks, tsum, C);
}

// Round 2
// 259.580 us; speedup vs baseline: 1.6050x; 1.6050x over previous
//
#include <hip/hip_runtime.h>
#include <math.h>

// Problem constants (from reference setup_inputs)
#define BB 4
#define NN 100
#define MM 20
#define HWPIX 65536
#define SSEG 8                    // HW segments per (b,n) -> occupancy
#define SEGPIX (HWPIX / SSEG)     // 8192 pixels per block
#define PSTRIDE 48                // padded partial stride (42 used)

typedef float v2f __attribute__((ext_vector_type(2)));

constexpr float ALPHA_C = 0.25f;

// ---------------------------------------------------------------------------
// Kernel 1: pack M binary masks into per-pixel 20-bit bitfield. No atomics.
// Grid: BB*256 blocks x 256 thr, 1 pixel/thread.
// ---------------------------------------------------------------------------
__global__ __launch_bounds__(256) void pack_targets_kernel(
    const float* __restrict__ tgt,       // [B][M][HW]
    unsigned int* __restrict__ masks)    // [B][HW]
{
    const int b = blockIdx.x >> 8;                       // 256 blocks per batch
    const int c = ((blockIdx.x & 255) << 8) | threadIdx.x;
    const float* tb = tgt + (size_t)b * MM * HWPIX + c;
    unsigned int mask = 0;
#pragma unroll
    for (int m = 0; m < MM; ++m)
        mask |= (tb[(size_t)m * HWPIX] > 0.5f) ? (1u << m) : 0u;
    masks[(size_t)b * HWPIX + c] = mask;
}

// ---------------------------------------------------------------------------
// Kernel 2: tsum[b][m] = sum_c t[b][m][c], from the packed bitfields.
// Grid: BB*MM blocks x 256 thr; integer popcount-style, deterministic.
// ---------------------------------------------------------------------------
__global__ __launch_bounds__(256) void tsum_kernel(
    const unsigned int* __restrict__ masks,   // [B][HW]
    float* __restrict__ tsum)                 // [B][M]
{
    const int b = blockIdx.x / MM;
    const int m = blockIdx.x % MM;
    const unsigned int* mp = masks + (size_t)b * HWPIX;
    int cnt = 0;
    for (int c = threadIdx.x; c < HWPIX; c += 256)
        cnt += (mp[c] >> m) & 1u;
    for (int off = 32; off > 0; off >>= 1) cnt += __shfl_down(cnt, off, 64);
    __shared__ int red[4];
    if ((threadIdx.x & 63) == 0) red[threadIdx.x >> 6] = cnt;
    __syncthreads();
    if (threadIdx.x == 0)
        tsum[blockIdx.x] = (float)(red[0] + red[1] + red[2] + red[3]);
}

// ---------------------------------------------------------------------------
// Kernel 3: per (b,n,segment) partial accumulation.
// Grid: BB*NN*SSEG = 3200 blocks x 256 thr  (~8 blocks/CU -> full wave cap)
//   d[m] = {sum t*(fp-fn), sum t*p};  sfn = sum fn; sp = sum p
// ---------------------------------------------------------------------------
__global__ __launch_bounds__(256) void cost_partial_kernel(
    const float* __restrict__ out,             // [B][N][HW]
    const unsigned int* __restrict__ masks,    // [B][HW]
    float* __restrict__ part)                  // [B*N][SSEG][PSTRIDE]
{
    const int bns = blockIdx.x;
    const int bn  = bns / SSEG;
    const int s   = bns % SSEG;
    const int b   = bn / NN;
    const int tid = threadIdx.x;

    const float* xp        = out + (size_t)bn * HWPIX + s * SEGPIX;
    const unsigned int* mp = masks + (size_t)b * HWPIX + s * SEGPIX;

    v2f d[MM];
#pragma unroll
    for (int m = 0; m < MM; ++m) d[m] = v2f{0.f, 0.f};
    float sum_fn = 0.f, sum_p = 0.f;

    for (int it = 0; it < SEGPIX / 256; ++it) {
        const int c = it * 256 + tid;          // coalesced
        const float x = xp[c];
        const unsigned int mk = mp[c];

        // Stable focal terms:
        //   e = exp(-|x|); L = log(1+e)
        //   bce_neg = softplus(x)  = relu(x) + L
        //   bce_pos = softplus(-x) = bce_neg - x
        //   p = (x>=0 ? 1 : e) / (1+e)
        const float ax  = fabsf(x);
        const float e   = __expf(-ax);
        const float ope = 1.f + e;
        const float L   = __logf(ope);
        const float bce_neg = fmaxf(x, 0.f) + L;
        const float bce_pos = bce_neg - x;
        const float inv = __builtin_amdgcn_rcpf(ope);
        const float p   = (x >= 0.f ? 1.f : e) * inv;
        const float omp = 1.f - p;
        const float fpv = ALPHA_C * omp * omp * bce_pos;
        const float fnv = (1.f - ALPHA_C) * p * p * bce_neg;

        sum_fn += fnv;
        sum_p  += p;

        const v2f dp = {fpv - fnv, p};
#pragma unroll
        for (int m = 0; m < MM; ++m) {
            const float tm = (float)((mk >> m) & 1u);   // bfe + cvt
            d[m] += tm * dp;                            // hope: v_pk_fma_f32
        }
    }

    // ---- block reduction: 42 values ----
    __shared__ float red[4][PSTRIDE];
    const int wave = tid >> 6;
    const int lane = tid & 63;

#pragma unroll
    for (int m = 0; m < MM; ++m) {
        for (int off = 32; off > 0; off >>= 1) {
            d[m].x += __shfl_down(d[m].x, off, 64);
            d[m].y += __shfl_down(d[m].y, off, 64);
        }
    }
    for (int off = 32; off > 0; off >>= 1) {
        sum_fn += __shfl_down(sum_fn, off, 64);
        sum_p  += __shfl_down(sum_p,  off, 64);
    }
    if (lane == 0) {
#pragma unroll
        for (int m = 0; m < MM; ++m) {
            red[wave][m]      = d[m].x;
            red[wave][MM + m] = d[m].y;
        }
        red[wave][40] = sum_fn;
        red[wave][41] = sum_p;
    }
    __syncthreads();

    if (tid < 42) {
        float v = red[0][tid] + red[1][tid] + red[2][tid] + red[3][tid];
        part[(size_t)bns * PSTRIDE + tid] = v;
    }
}

// ---------------------------------------------------------------------------
// Kernel 4: combine partials -> C[bn][m]. Deterministic, tiny.
// ---------------------------------------------------------------------------
__global__ __launch_bounds__(256) void combine_kernel(
    const float* __restrict__ part,    // [B*N][SSEG][PSTRIDE]
    const float* __restrict__ tsum,    // [B][M]
    float* __restrict__ C)             // [B*N][M]
{
    const int g = blockIdx.x * 256 + threadIdx.x;
    if (g >= BB * NN * MM) return;
    const int bn = g / MM;
    const int m  = g - bn * MM;
    const int b  = bn / NN;

    float D1 = 0.f, D2 = 0.f, SFN = 0.f, SP = 0.f;
#pragma unroll
    for (int s = 0; s < SSEG; ++s) {
        const float* pp = part + ((size_t)bn * SSEG + s) * PSTRIDE;
        D1  += pp[m];
        D2  += pp[MM + m];
        SFN += pp[40];
        SP  += pp[41];
    }
    const float cost_mask = (SFN + D1) * (1.f / (float)HWPIX);
    const float den  = SP + tsum[b * MM + m];
    const float dice = 1.f - (2.f * D2 + 1.f) / (den + 1.f);
    C[g] = cost_mask + dice;
}

extern "C" void kernel_launch(void* const* d_in, const int* in_sizes, int n_in,
                              void* d_out, int out_size, void* d_ws, size_t ws_size,
                              hipStream_t stream)
{
    const float* outp = (const float*)d_in[0];   // [B][N][H][W]
    const float* tgtp = (const float*)d_in[1];   // [B][M][H][W]
    float* C = (float*)d_out;                    // [B][N][M]

    char* ws = (char*)d_ws;
    unsigned int* masks = (unsigned int*)ws;                          // 1 MB
    float* tsum = (float*)(ws + (size_t)BB * HWPIX * sizeof(unsigned int));          // 320 B
    float* part = (float*)(ws + (size_t)BB * HWPIX * sizeof(unsigned int) + 512);    // 614 KB

    pack_targets_kernel<<<BB * 256, 256, 0, stream>>>(tgtp, masks);
    tsum_kernel<<<BB * MM, 256, 0, stream>>>(masks, tsum);
    cost_partial_kernel<<<BB * NN * SSEG, 256, 0, stream>>>(outp, masks, part);
    combine_kernel<<<(BB * NN * MM + 255) / 256, 256, 0, stream>>>(part, tsum, C);
}